// Round 1
// baseline (106.940 us; speedup 1.0000x reference)
//
#include <hip/hip_runtime.h>

#define NN 2048
#define CC 64

// ---------------------------------------------------------------------------
// Kernel 1: per-node dot products of embs rows with the 4 factor halves.
// ws layout: r_lo[NN] | r_hi[NN] | d_lo[NN] | d_hi[NN]
// One wave (64 lanes) per node; lane index == channel index since C==64.
// ---------------------------------------------------------------------------
__global__ void node_dots_kernel(const float* __restrict__ embs,
                                 const float* __restrict__ depth_factor,
                                 const float* __restrict__ radius_factor,
                                 float* __restrict__ ws) {
    int node = (blockIdx.x * blockDim.x + threadIdx.x) >> 6;
    int lane = threadIdx.x & 63;
    if (node >= NN) return;

    float e  = embs[node * CC + lane];
    float rl = e * radius_factor[lane];        // radius_factor[:C]
    float rh = e * radius_factor[CC + lane];   // radius_factor[C:]
    float dl = e * depth_factor[lane];
    float dh = e * depth_factor[CC + lane];

    #pragma unroll
    for (int off = 32; off > 0; off >>= 1) {
        rl += __shfl_down(rl, off, 64);
        rh += __shfl_down(rh, off, 64);
        dl += __shfl_down(dl, off, 64);
        dh += __shfl_down(dh, off, 64);
    }
    if (lane == 0) {
        ws[node]          = rl;
        ws[NN + node]     = rh;
        ws[2 * NN + node] = dl;
        ws[3 * NN + node] = dh;
    }
}

// ---------------------------------------------------------------------------
// Kernel 2: pair energy reduction. One block per row i, threads stride over j.
//   D      = sqrt(|X_j - X_i|^2 + 3e-6)
//   sig_r  = sigmoid(r_hi[i] + r_lo[j]);  sig_d = sigmoid(d_hi[i] + d_lo[j])
//   s      = (s0[i]+s0[j]) * (0.8*sig_r + 0.4)
//   repl   = 5*exp(-0.3*D^3) * mask
//   Dm     = D - s
//   attr   = (exp(-(Dm-0.3)^2) + exp(-3 Dm^2) + exp(-10 Dm^2))/3 * mask
//   w      = sqrt(w0[i]*w0[j] + 1e-6) * (sig_d + 0.5)
//   E     += repl - w*attr
// ---------------------------------------------------------------------------
__global__ void pair_energy_kernel(const float* __restrict__ X,
                                   const float* __restrict__ w0,
                                   const float* __restrict__ s0,
                                   const float* __restrict__ mask,
                                   const float* __restrict__ ws,
                                   float* __restrict__ out) {
    const float* __restrict__ r_lo = ws;
    const float* __restrict__ r_hi = ws + NN;
    const float* __restrict__ d_lo = ws + 2 * NN;
    const float* __restrict__ d_hi = ws + 3 * NN;

    const int i = blockIdx.x;
    const float xi  = X[3 * i];
    const float yi  = X[3 * i + 1];
    const float zi  = X[3 * i + 2];
    const float rhi = r_hi[i];
    const float dhi = d_hi[i];
    const float s0i = s0[i];
    const float w0i = w0[i];

    float acc = 0.0f;
    const float* mrow = mask + (size_t)i * NN;

    for (int j = threadIdx.x; j < NN; j += blockDim.x) {
        float dx = X[3 * j]     - xi;
        float dy = X[3 * j + 1] - yi;
        float dz = X[3 * j + 2] - zi;
        float d2 = dx * dx + dy * dy + dz * dz + 3e-6f;
        float D  = __builtin_amdgcn_sqrtf(d2);

        float er    = __expf(-(rhi + r_lo[j]));
        float sig_r = __builtin_amdgcn_rcpf(1.0f + er);
        float ed    = __expf(-(dhi + d_lo[j]));
        float sig_d = __builtin_amdgcn_rcpf(1.0f + ed);

        float m = mrow[j];

        float s  = (s0i + s0[j]) * (0.8f * sig_r + 0.4f);
        float Dm = D - s;
        float t  = Dm - 0.3f;

        float repl = 5.0f * __expf(-0.3f * d2 * D) * m;
        float attr = (__expf(-t * t)
                    + __expf(-3.0f * Dm * Dm)
                    + __expf(-10.0f * Dm * Dm)) * (1.0f / 3.0f) * m;

        float w = __builtin_amdgcn_sqrtf(w0i * w0[j] + 1e-6f) * (sig_d + 0.5f);

        acc += repl - w * attr;
    }

    // wave reduce (64 lanes), then LDS across the 4 waves of the block
    #pragma unroll
    for (int off = 32; off > 0; off >>= 1) acc += __shfl_down(acc, off, 64);

    __shared__ float red[4];
    int lane = threadIdx.x & 63;
    int wid  = threadIdx.x >> 6;
    if (lane == 0) red[wid] = acc;
    __syncthreads();
    if (threadIdx.x == 0) {
        float v = red[0] + red[1] + red[2] + red[3];
        atomicAdd(out, v);
    }
}

extern "C" void kernel_launch(void* const* d_in, const int* in_sizes, int n_in,
                              void* d_out, int out_size, void* d_ws, size_t ws_size,
                              hipStream_t stream) {
    const float* X             = (const float*)d_in[0];
    const float* embs          = (const float*)d_in[1];
    const float* w0            = (const float*)d_in[2];
    const float* s0            = (const float*)d_in[3];
    const float* paired_mask   = (const float*)d_in[4];
    const float* depth_factor  = (const float*)d_in[5];
    const float* radius_factor = (const float*)d_in[6];

    float* out = (float*)d_out;
    float* ws  = (float*)d_ws;

    // d_out is re-poisoned to 0xAA before every timed launch — zero it.
    hipMemsetAsync(out, 0, sizeof(float), stream);

    // Kernel 1: 2048 nodes, one wave each -> 512 blocks of 256 threads.
    node_dots_kernel<<<dim3(NN / 4), dim3(256), 0, stream>>>(
        embs, depth_factor, radius_factor, ws);

    // Kernel 2: one block per row.
    pair_energy_kernel<<<dim3(NN), dim3(256), 0, stream>>>(
        X, w0, s0, paired_mask, ws, out);
}

// Round 2
// 105.389 us; speedup vs baseline: 1.0147x; 1.0147x over previous
//
#include <hip/hip_runtime.h>

#define NN 2048
#define CC 64

// ws layout:
//   float4 pj[NN]   : (r_lo[j], d_lo[j], s0[j], w0[j])        -- 32 KB
//   float  ih[2*NN] : r_hi[NN] | d_hi[NN]                     -- 16 KB
//
// Kernel 1 (prep): per-node dot products of embs rows with the 4 factor
// halves (one wave per node, lane == channel since C == 64), packs the
// per-j float4, and zeroes d_out (d_out is poisoned 0xAA before each call).
__global__ void prep_kernel(const float* __restrict__ embs,
                            const float* __restrict__ depth_factor,
                            const float* __restrict__ radius_factor,
                            const float* __restrict__ s0,
                            const float* __restrict__ w0,
                            float4* __restrict__ pj,
                            float* __restrict__ ih,
                            float* __restrict__ out) {
    int gid = blockIdx.x * blockDim.x + threadIdx.x;
    if (gid == 0) out[0] = 0.0f;

    int node = gid >> 6;
    int lane = threadIdx.x & 63;
    if (node >= NN) return;

    float e  = embs[node * CC + lane];
    float rl = e * radius_factor[lane];        // radius_factor[:C]  -> j term
    float rh = e * radius_factor[CC + lane];   // radius_factor[C:]  -> i term
    float dl = e * depth_factor[lane];
    float dh = e * depth_factor[CC + lane];

    #pragma unroll
    for (int off = 32; off > 0; off >>= 1) {
        rl += __shfl_down(rl, off, 64);
        rh += __shfl_down(rh, off, 64);
        dl += __shfl_down(dl, off, 64);
        dh += __shfl_down(dh, off, 64);
    }
    if (lane == 0) {
        pj[node] = make_float4(rl, dl, s0[node], w0[node]);
        ih[node]      = rh;
        ih[NN + node] = dh;
    }
}

// Per-pair energy. 5 exps (exp(-3Dm^2)=e1^3, exp(-10Dm^2)=e1^10,
// exp(-(Dm-0.3)^2)=e1*exp(0.6Dm-0.09) with e1=exp(-Dm^2)).
__device__ __forceinline__ float pair_e(float xj, float yj, float zj,
                                        float4 p, float m,
                                        float xi, float yi, float zi,
                                        float rhi, float dhi,
                                        float s0i, float w0i) {
    float dx = xj - xi, dy = yj - yi, dz = zj - zi;
    float d2 = fmaf(dx, dx, fmaf(dy, dy, fmaf(dz, dz, 3e-6f)));
    float D  = __builtin_amdgcn_sqrtf(d2);

    float sig_r = __builtin_amdgcn_rcpf(1.0f + __expf(-(rhi + p.x)));
    float sig_d = __builtin_amdgcn_rcpf(1.0f + __expf(-(dhi + p.y)));

    float s  = (s0i + p.z) * fmaf(0.8f, sig_r, 0.4f);
    float Dm = D - s;

    float repl = 5.0f * __expf(-0.3f * d2 * D);

    float e1 = __expf(-Dm * Dm);
    float g  = __expf(fmaf(0.6f, Dm, -0.09f));
    float e2 = e1 * e1;
    float e4 = e2 * e2;
    float e8 = e4 * e4;
    float attr3 = fmaf(e1, g, e2 * e1) + e8 * e2;   // sum of the 3 gaussians

    float w = __builtin_amdgcn_sqrtf(fmaf(w0i, p.w, 1e-6f)) * (sig_d + 0.5f);

    return m * fmaf(-w * (1.0f / 3.0f), attr3, repl);
}

__global__ __launch_bounds__(256) void pair_energy_kernel(
        const float* __restrict__ X,
        const float* __restrict__ mask,
        const float4* __restrict__ pj,
        const float* __restrict__ ih,
        float* __restrict__ out) {
    const int i = blockIdx.x;
    const float xi  = X[3 * i];
    const float yi  = X[3 * i + 1];
    const float zi  = X[3 * i + 2];
    const float rhi = ih[i];
    const float dhi = ih[NN + i];
    const float4 pi = pj[i];
    const float s0i = pi.z;
    const float w0i = pi.w;

    const float4* __restrict__ mrow = (const float4*)(mask + (size_t)i * NN);
    const float4* __restrict__ X4   = (const float4*)X;

    float acc = 0.0f;
    #pragma unroll
    for (int it = 0; it < NN / (4 * 256); ++it) {
        int j4 = threadIdx.x + it * 256;          // group of 4 consecutive j
        float4 m  = mrow[j4];
        float4 xa = X4[3 * j4];
        float4 xb = X4[3 * j4 + 1];
        float4 xc = X4[3 * j4 + 2];
        float4 p0 = pj[4 * j4];
        float4 p1 = pj[4 * j4 + 1];
        float4 p2 = pj[4 * j4 + 2];
        float4 p3 = pj[4 * j4 + 3];

        acc += pair_e(xa.x, xa.y, xa.z, p0, m.x, xi, yi, zi, rhi, dhi, s0i, w0i);
        acc += pair_e(xa.w, xb.x, xb.y, p1, m.y, xi, yi, zi, rhi, dhi, s0i, w0i);
        acc += pair_e(xb.z, xb.w, xc.x, p2, m.z, xi, yi, zi, rhi, dhi, s0i, w0i);
        acc += pair_e(xc.y, xc.z, xc.w, p3, m.w, xi, yi, zi, rhi, dhi, s0i, w0i);
    }

    #pragma unroll
    for (int off = 32; off > 0; off >>= 1) acc += __shfl_down(acc, off, 64);

    __shared__ float red[4];
    int lane = threadIdx.x & 63;
    int wid  = threadIdx.x >> 6;
    if (lane == 0) red[wid] = acc;
    __syncthreads();
    if (threadIdx.x == 0) {
        atomicAdd(out, red[0] + red[1] + red[2] + red[3]);
    }
}

extern "C" void kernel_launch(void* const* d_in, const int* in_sizes, int n_in,
                              void* d_out, int out_size, void* d_ws, size_t ws_size,
                              hipStream_t stream) {
    const float* X             = (const float*)d_in[0];
    const float* embs          = (const float*)d_in[1];
    const float* w0            = (const float*)d_in[2];
    const float* s0            = (const float*)d_in[3];
    const float* paired_mask   = (const float*)d_in[4];
    const float* depth_factor  = (const float*)d_in[5];
    const float* radius_factor = (const float*)d_in[6];

    float*  out = (float*)d_out;
    float4* pj  = (float4*)d_ws;
    float*  ih  = (float*)d_ws + 4 * NN;

    // Kernel 1: 2048 nodes, one wave each -> 512 blocks of 256 threads.
    // Also zeroes d_out (poisoned 0xAA by the harness before every launch).
    prep_kernel<<<dim3(NN / 4), dim3(256), 0, stream>>>(
        embs, depth_factor, radius_factor, s0, w0, pj, ih, out);

    // Kernel 2: one block per row i.
    pair_energy_kernel<<<dim3(NN), dim3(256), 0, stream>>>(
        X, paired_mask, pj, ih, out);
}

// Round 3
// 93.031 us; speedup vs baseline: 1.1495x; 1.1328x over previous
//
#include <hip/hip_runtime.h>

#define NN 2048
#define CC 64

// ws layout:
//   float4 pj[NN]   : (Er_lo[j]=exp(-r_lo[j]), Ed_lo[j]=exp(-d_lo[j]),
//                      s0[j], sw[j]=sqrt(w0[j]))                  -- 32 KB
//   float  ih[2*NN] : Er_hi[NN]=exp(-r_hi) | Ed_hi[NN]=exp(-d_hi) -- 16 KB
//
// Sigmoid separation: sigmoid(rhi+rlo) = 1/(1 + e^{-rhi}·e^{-rlo}); dots are
// ~N(0,8^2) so the pair product <= ~e^64 ~ 6e27 < FLT_MAX (no overflow;
// underflow->0 gives sigmoid->1, exact). sqrt(w0i*w0j+1e-6) ~= sw_i*sw_j
// (error <= 1e-3/pair worst case, ~1e-6 typical; threshold is 3.6e4).
__global__ void prep_kernel(const float* __restrict__ embs,
                            const float* __restrict__ depth_factor,
                            const float* __restrict__ radius_factor,
                            const float* __restrict__ s0,
                            const float* __restrict__ w0,
                            float4* __restrict__ pj,
                            float* __restrict__ ih,
                            float* __restrict__ out) {
    int gid = blockIdx.x * blockDim.x + threadIdx.x;
    if (gid == 0) out[0] = 0.0f;   // d_out poisoned 0xAA before every call

    int node = gid >> 6;
    int lane = threadIdx.x & 63;
    if (node >= NN) return;

    float e  = embs[node * CC + lane];
    float rl = e * radius_factor[lane];        // radius_factor[:C]  -> j term
    float rh = e * radius_factor[CC + lane];   // radius_factor[C:]  -> i term
    float dl = e * depth_factor[lane];
    float dh = e * depth_factor[CC + lane];

    #pragma unroll
    for (int off = 32; off > 0; off >>= 1) {
        rl += __shfl_down(rl, off, 64);
        rh += __shfl_down(rh, off, 64);
        dl += __shfl_down(dl, off, 64);
        dh += __shfl_down(dh, off, 64);
    }
    if (lane == 0) {
        pj[node] = make_float4(__expf(-rl), __expf(-dl),
                               s0[node], __builtin_amdgcn_sqrtf(w0[node]));
        ih[node]      = __expf(-rh);
        ih[NN + node] = __expf(-dh);
    }
}

// Per-pair energy: 3 exps + 2 rcp + 1 sqrt on the quarter-rate pipe.
//   exp(-3Dm^2)=e1^3, exp(-10Dm^2)=e1^10, exp(-(Dm-0.3)^2)=e1*exp(0.6Dm-0.09)
__device__ __forceinline__ float pair_e(float xj, float yj, float zj,
                                        float4 p, float m,
                                        float xi, float yi, float zi,
                                        float Eri, float Edi,
                                        float s0i, float swi) {
    float dx = xj - xi, dy = yj - yi, dz = zj - zi;
    float d2 = fmaf(dx, dx, fmaf(dy, dy, fmaf(dz, dz, 3e-6f)));
    float D  = __builtin_amdgcn_sqrtf(d2);

    float sig_r = __builtin_amdgcn_rcpf(fmaf(Eri, p.x, 1.0f));
    float sig_d = __builtin_amdgcn_rcpf(fmaf(Edi, p.y, 1.0f));

    float s  = (s0i + p.z) * fmaf(0.8f, sig_r, 0.4f);
    float Dm = D - s;

    float repl = 5.0f * __expf(-0.3f * d2 * D);

    float e1 = __expf(-Dm * Dm);
    float g  = __expf(fmaf(0.6f, Dm, -0.09f));
    float e2 = e1 * e1;
    float e4 = e2 * e2;
    float e8 = e4 * e4;
    float attr3 = fmaf(e1, g, e2 * e1) + e8 * e2;   // sum of the 3 gaussians

    float w = swi * p.w * (sig_d + 0.5f);

    return m * fmaf(-w * (1.0f / 3.0f), attr3, repl);
}

// Two rows i per block (1024 blocks): j-side loads (X, pj) amortized 2x.
__global__ __launch_bounds__(256) void pair_energy_kernel(
        const float* __restrict__ X,
        const float* __restrict__ mask,
        const float4* __restrict__ pj,
        const float* __restrict__ ih,
        float* __restrict__ out) {
    const int i0 = 2 * blockIdx.x;
    const int i1 = i0 + 1;

    const float x0 = X[3 * i0], y0 = X[3 * i0 + 1], z0 = X[3 * i0 + 2];
    const float x1 = X[3 * i1], y1 = X[3 * i1 + 1], z1 = X[3 * i1 + 2];
    const float Er0 = ih[i0],      Er1 = ih[i1];
    const float Ed0 = ih[NN + i0], Ed1 = ih[NN + i1];
    const float4 q0 = pj[i0], q1 = pj[i1];

    const float4* __restrict__ mrow0 = (const float4*)(mask + (size_t)i0 * NN);
    const float4* __restrict__ mrow1 = (const float4*)(mask + (size_t)i1 * NN);
    const float4* __restrict__ X4    = (const float4*)X;

    float acc = 0.0f;
    #pragma unroll
    for (int it = 0; it < NN / (4 * 256); ++it) {
        int j4 = threadIdx.x + it * 256;          // group of 4 consecutive j
        float4 m0 = mrow0[j4];
        float4 m1 = mrow1[j4];
        float4 xa = X4[3 * j4];
        float4 xb = X4[3 * j4 + 1];
        float4 xc = X4[3 * j4 + 2];
        float4 p0 = pj[4 * j4];
        float4 p1 = pj[4 * j4 + 1];
        float4 p2 = pj[4 * j4 + 2];
        float4 p3 = pj[4 * j4 + 3];

        acc += pair_e(xa.x, xa.y, xa.z, p0, m0.x, x0, y0, z0, Er0, Ed0, q0.z, q0.w);
        acc += pair_e(xa.w, xb.x, xb.y, p1, m0.y, x0, y0, z0, Er0, Ed0, q0.z, q0.w);
        acc += pair_e(xb.z, xb.w, xc.x, p2, m0.z, x0, y0, z0, Er0, Ed0, q0.z, q0.w);
        acc += pair_e(xc.y, xc.z, xc.w, p3, m0.w, x0, y0, z0, Er0, Ed0, q0.z, q0.w);

        acc += pair_e(xa.x, xa.y, xa.z, p0, m1.x, x1, y1, z1, Er1, Ed1, q1.z, q1.w);
        acc += pair_e(xa.w, xb.x, xb.y, p1, m1.y, x1, y1, z1, Er1, Ed1, q1.z, q1.w);
        acc += pair_e(xb.z, xb.w, xc.x, p2, m1.z, x1, y1, z1, Er1, Ed1, q1.z, q1.w);
        acc += pair_e(xc.y, xc.z, xc.w, p3, m1.w, x1, y1, z1, Er1, Ed1, q1.z, q1.w);
    }

    #pragma unroll
    for (int off = 32; off > 0; off >>= 1) acc += __shfl_down(acc, off, 64);

    __shared__ float red[4];
    int lane = threadIdx.x & 63;
    int wid  = threadIdx.x >> 6;
    if (lane == 0) red[wid] = acc;
    __syncthreads();
    if (threadIdx.x == 0) {
        atomicAdd(out, red[0] + red[1] + red[2] + red[3]);
    }
}

extern "C" void kernel_launch(void* const* d_in, const int* in_sizes, int n_in,
                              void* d_out, int out_size, void* d_ws, size_t ws_size,
                              hipStream_t stream) {
    const float* X             = (const float*)d_in[0];
    const float* embs          = (const float*)d_in[1];
    const float* w0            = (const float*)d_in[2];
    const float* s0            = (const float*)d_in[3];
    const float* paired_mask   = (const float*)d_in[4];
    const float* depth_factor  = (const float*)d_in[5];
    const float* radius_factor = (const float*)d_in[6];

    float*  out = (float*)d_out;
    float4* pj  = (float4*)d_ws;
    float*  ih  = (float*)d_ws + 4 * NN;

    // Kernel 1: one wave per node (2048 waves = 512 blocks of 256).
    prep_kernel<<<dim3(NN / 4), dim3(256), 0, stream>>>(
        embs, depth_factor, radius_factor, s0, w0, pj, ih, out);

    // Kernel 2: two rows per block.
    pair_energy_kernel<<<dim3(NN / 2), dim3(256), 0, stream>>>(
        X, paired_mask, pj, ih, out);
}

// Round 4
// 91.822 us; speedup vs baseline: 1.1646x; 1.0132x over previous
//
#include <hip/hip_runtime.h>

#define NN 2048
#define CC 64

// ws layout:
//   float4 pj[NN]   : (Er_lo[j]=exp(-r_lo[j]), Ed_lo[j]=exp(-d_lo[j]),
//                      s0[j], sw[j]=sqrt(w0[j]))                  -- 32 KB
//   float  ih[2*NN] : Er_hi[NN]=exp(-r_hi) | Ed_hi[NN]=exp(-d_hi) -- 16 KB
__global__ void prep_kernel(const float* __restrict__ embs,
                            const float* __restrict__ depth_factor,
                            const float* __restrict__ radius_factor,
                            const float* __restrict__ s0,
                            const float* __restrict__ w0,
                            float4* __restrict__ pj,
                            float* __restrict__ ih,
                            float* __restrict__ out) {
    int gid = blockIdx.x * blockDim.x + threadIdx.x;
    if (gid == 0) out[0] = 0.0f;   // d_out poisoned 0xAA before every call

    int node = gid >> 6;
    int lane = threadIdx.x & 63;
    if (node >= NN) return;

    float e  = embs[node * CC + lane];
    float rl = e * radius_factor[lane];        // radius_factor[:C]  -> j term
    float rh = e * radius_factor[CC + lane];   // radius_factor[C:]  -> i term
    float dl = e * depth_factor[lane];
    float dh = e * depth_factor[CC + lane];

    #pragma unroll
    for (int off = 32; off > 0; off >>= 1) {
        rl += __shfl_down(rl, off, 64);
        rh += __shfl_down(rh, off, 64);
        dl += __shfl_down(dl, off, 64);
        dh += __shfl_down(dh, off, 64);
    }
    if (lane == 0) {
        pj[node] = make_float4(__expf(-rl), __expf(-dl),
                               s0[node], __builtin_amdgcn_sqrtf(w0[node]));
        ih[node]      = __expf(-rh);
        ih[NN + node] = __expf(-dh);
    }
}

// Per-pair energy: 3 exp + 1 rcp + 1 sqrt on the quarter-rate pipe.
// Both sigmoids from ONE rcp: a=1+Er_i*Er_j, b=1+Ed_i*Ed_j,
//   rinv=rcp(a*b); sig_r=rinv*b; sig_d=rinv*a.
// (a*b <= ~e^52 here; overflow needs 8-sigma dot sums — not reachable.)
//   exp(-3Dm^2)=e1^3, exp(-10Dm^2)=e1^10, exp(-(Dm-0.3)^2)=e1*exp(0.6Dm-0.09)
__device__ __forceinline__ float pair_e(float xj, float yj, float zj,
                                        float4 p, float m,
                                        float xi, float yi, float zi,
                                        float Eri, float Edi,
                                        float s0i, float swi) {
    float dx = xj - xi, dy = yj - yi, dz = zj - zi;
    float d2 = fmaf(dx, dx, fmaf(dy, dy, fmaf(dz, dz, 3e-6f)));
    float D  = __builtin_amdgcn_sqrtf(d2);

    float a = fmaf(Eri, p.x, 1.0f);
    float b = fmaf(Edi, p.y, 1.0f);
    float rinv = __builtin_amdgcn_rcpf(a * b);
    float sig_r = rinv * b;
    float sig_d = rinv * a;

    float s  = (s0i + p.z) * fmaf(0.8f, sig_r, 0.4f);
    float Dm = D - s;

    float repl = 5.0f * __expf(-0.3f * d2 * D);

    float e1 = __expf(-Dm * Dm);
    float g  = __expf(fmaf(0.6f, Dm, -0.09f));
    float e2 = e1 * e1;
    float e4 = e2 * e2;
    float e8 = e4 * e4;
    float attr3 = fmaf(e1, g, e2 * e1) + e8 * e2;   // sum of the 3 gaussians

    float w = swi * p.w * (sig_d + 0.5f);

    return m * fmaf(-w * (1.0f / 3.0f), attr3, repl);
}

// 4 rows x 1024 j per block; grid (512 row-groups, 2 j-halves) = 1024 blocks.
// Each thread handles exactly one float4 j-group (4 j) x 4 rows = 16 pairs;
// X/pj loads amortized 4x across rows, straight-line body (no j loop).
__global__ __launch_bounds__(256) void pair_energy_kernel(
        const float* __restrict__ X,
        const float* __restrict__ mask,
        const float4* __restrict__ pj,
        const float* __restrict__ ih,
        float* __restrict__ out) {
    const int i0 = 4 * blockIdx.x;
    const int j4 = (blockIdx.y << 8) + threadIdx.x;   // float4 index in j

    const float4* __restrict__ X4 = (const float4*)X;
    float4 m0 = ((const float4*)(mask + (size_t)(i0 + 0) * NN))[j4];
    float4 m1 = ((const float4*)(mask + (size_t)(i0 + 1) * NN))[j4];
    float4 m2 = ((const float4*)(mask + (size_t)(i0 + 2) * NN))[j4];
    float4 m3 = ((const float4*)(mask + (size_t)(i0 + 3) * NN))[j4];
    float4 xa = X4[3 * j4];
    float4 xb = X4[3 * j4 + 1];
    float4 xc = X4[3 * j4 + 2];
    float4 p0 = pj[4 * j4];
    float4 p1 = pj[4 * j4 + 1];
    float4 p2 = pj[4 * j4 + 2];
    float4 p3 = pj[4 * j4 + 3];

    float acc = 0.0f;
    #pragma unroll
    for (int r = 0; r < 4; ++r) {
        const int i = i0 + r;
        const float xi = X[3 * i], yi = X[3 * i + 1], zi = X[3 * i + 2];
        const float Eri = ih[i], Edi = ih[NN + i];
        const float4 qi = pj[i];
        const float4 mr = (r == 0) ? m0 : (r == 1) ? m1 : (r == 2) ? m2 : m3;

        acc += pair_e(xa.x, xa.y, xa.z, p0, mr.x, xi, yi, zi, Eri, Edi, qi.z, qi.w);
        acc += pair_e(xa.w, xb.x, xb.y, p1, mr.y, xi, yi, zi, Eri, Edi, qi.z, qi.w);
        acc += pair_e(xb.z, xb.w, xc.x, p2, mr.z, xi, yi, zi, Eri, Edi, qi.z, qi.w);
        acc += pair_e(xc.y, xc.z, xc.w, p3, mr.w, xi, yi, zi, Eri, Edi, qi.z, qi.w);
    }

    #pragma unroll
    for (int off = 32; off > 0; off >>= 1) acc += __shfl_down(acc, off, 64);

    __shared__ float red[4];
    int lane = threadIdx.x & 63;
    int wid  = threadIdx.x >> 6;
    if (lane == 0) red[wid] = acc;
    __syncthreads();
    if (threadIdx.x == 0) {
        atomicAdd(out, red[0] + red[1] + red[2] + red[3]);
    }
}

extern "C" void kernel_launch(void* const* d_in, const int* in_sizes, int n_in,
                              void* d_out, int out_size, void* d_ws, size_t ws_size,
                              hipStream_t stream) {
    const float* X             = (const float*)d_in[0];
    const float* embs          = (const float*)d_in[1];
    const float* w0            = (const float*)d_in[2];
    const float* s0            = (const float*)d_in[3];
    const float* paired_mask   = (const float*)d_in[4];
    const float* depth_factor  = (const float*)d_in[5];
    const float* radius_factor = (const float*)d_in[6];

    float*  out = (float*)d_out;
    float4* pj  = (float4*)d_ws;
    float*  ih  = (float*)d_ws + 4 * NN;

    // Kernel 1: one wave per node (2048 waves = 512 blocks of 256).
    prep_kernel<<<dim3(NN / 4), dim3(256), 0, stream>>>(
        embs, depth_factor, radius_factor, s0, w0, pj, ih, out);

    // Kernel 2: 4 rows x 1024 j per block.
    pair_energy_kernel<<<dim3(NN / 4, 2), dim3(256), 0, stream>>>(
        X, paired_mask, pj, ih, out);
}